// Round 11
// baseline (724.594 us; speedup 1.0000x reference)
//
#include <hip/hip_runtime.h>
#include <hip/hip_bf16.h>
#include <type_traits>

#define NE 8
#define DIN 1024
#define DHID 4096
#define DOUTD 1024
#define NTOK 32768
#define CAP (NTOK / NE)  // 4096 tokens per expert

typedef unsigned short u16;
typedef __attribute__((ext_vector_type(8))) short bf16x8;   // 8 bf16 = 4 VGPR
typedef __attribute__((ext_vector_type(4))) float f32x4;

template <int I> using ic = std::integral_constant<int, I>;

__device__ __forceinline__ u16 f2bf(float x) {
  unsigned u = __builtin_bit_cast(unsigned, x);
  u += 0x7fffu + ((u >> 16) & 1u);   // RNE; finite normals
  return (u16)(u >> 16);
}

// tanh-form GELU (max dev from erf-form ~3e-4; threshold headroom ~4.6x; R4-R10-verified)
__device__ __forceinline__ float gelu_f(float x) {
  float u = 0.7978845608028654f * x * (1.0f + 0.044715f * x * x);
  float t = __expf(-2.0f * fabsf(u));
  float r = __fdividef(2.0f * t, 1.0f + t);   // 1 - tanh|u|
  float th = copysignf(1.0f - r, u);
  return 0.5f * x * (1.0f + th);
}

__device__ __forceinline__ void async_ld16(const void* g, void* l) {
  __builtin_amdgcn_global_load_lds(
      (const __attribute__((address_space(1))) unsigned int*)g,
      (__attribute__((address_space(3))) unsigned int*)l, 16, 0, 0);
}

// ---------------- fp32 -> bf16, 8 elems/thread ----------------
__global__ __launch_bounds__(256) void convert_bf16_kernel(const float* __restrict__ in,
                                                           u16* __restrict__ out) {
  size_t i = ((size_t)blockIdx.x * 256 + threadIdx.x) * 8;
  float4 a = *(const float4*)(in + i);
  float4 b = *(const float4*)(in + i + 4);
  uint4 o;
  o.x = (unsigned)f2bf(a.x) | ((unsigned)f2bf(a.y) << 16);
  o.y = (unsigned)f2bf(a.z) | ((unsigned)f2bf(a.w) << 16);
  o.z = (unsigned)f2bf(b.x) | ((unsigned)f2bf(b.y) << 16);
  o.w = (unsigned)f2bf(b.z) | ((unsigned)f2bf(b.w) << 16);
  *(uint4*)(out + i) = o;
}

// ------------- [E][K][N] fp32 -> [E][N][K] bf16 (64x64 LDS-tiled) -------------
__global__ __launch_bounds__(256) void transpose_bf16_kernel(const float* __restrict__ in,
                                                             u16* __restrict__ out,
                                                             int K, int N) {
  __shared__ __align__(16) u16 tile[64 * 72];
  const int e = blockIdx.z;
  const int n0 = blockIdx.x * 64;
  const int k0 = blockIdx.y * 64;
  const float* inp = in + (size_t)e * K * N;
  u16* outp = out + (size_t)e * N * K;
  const int t = threadIdx.x;
  const int kr = t >> 4;
  const int nc = (t & 15) * 4;
#pragma unroll
  for (int rr = 0; rr < 4; ++rr) {
    int kl = rr * 16 + kr;
    float4 v = *(const float4*)(inp + (size_t)(k0 + kl) * N + n0 + nc);
    tile[(nc + 0) * 72 + kl] = f2bf(v.x);
    tile[(nc + 1) * 72 + kl] = f2bf(v.y);
    tile[(nc + 2) * 72 + kl] = f2bf(v.z);
    tile[(nc + 3) * 72 + kl] = f2bf(v.w);
  }
  __syncthreads();
  const int nr = t >> 3;
  const int kc = (t & 7) * 8;
#pragma unroll
  for (int it = 0; it < 2; ++it) {
    int nl = it * 32 + nr;
    bf16x8 w = *(const bf16x8*)(tile + nl * 72 + kc);
    *(bf16x8*)(outp + (size_t)(n0 + nl) * K + k0 + kc) = w;
  }
}

// -------- grouped GEMM, 256x256, BK=64, dbuf-2, 4-phase + m201 DOUBLE-BARRIER bracket --------
// C[e] = A[e] (CAP x K bf16 row-major) @ Bt[e]^T (Bt: N x K bf16 row-major).
// 8 waves (2M x 4N), per-wave 128x64, MFMA 16x16x32, acc f32x4[8][4] (128 AGPR).
// R9 lesson: unified regs (~104 VGPR + 128 AGPR) => 2 waves/SIMD, 1 block/CU. Optimize
// the intra-block schedule. R10 (817 TF) == m248 reference band; R11 adds the ONE
// remaining m201 structural element: a CLOSING s_barrier after each 16-MFMA cluster
// (phase = {ds+stage | bar | lgkm0 | MFMA | bar}, 2 barriers/phase) — m196's A/B
// isolated this fine bracket as the 8-phase lever. Everything else identical to R10.
// LDS: 2 buffers x 64KB; buffer = 4 regions of 16KB: {A_kc0@0, A_kc1@16K,
// B_kc0@32K, B_kc1@48K}. Region layout (R1-R10, 0 conflicts): [128 lds-rows]
// [8 x 16B units]; global (r,k in 32-chunk): lds_row=r&127, lu=(r>>7)*4+(k>>3),
// phys unit=lu^(lds_row&7) (T2); staged linear-dest + inverse-swizzled global src
// (rule #21). Phase (kc,*) reads ONLY region kc => staging order A_kc0,B_kc0,
// A_kc1,B_kc1 gives counted gates (never drain, T4) with 2-3 phase cover.
// Per K-tile t (read buf P=t&1, stage t+1 into Q=P^1), 4 phases (kc,mh):
//  (0,0): stage A_kc0(t+1) | ds bfr0[4]+afr0[0-3] | bar | lgkm0 | 16 MFMA | bar
//  (0,1): stage B_kc0(t+1) | ds afr0[4-7] | vmcnt(4)+bar | lgkm0 | 16 MFMA | bar
//  (1,0): stage A_kc1(t+1) | ds bfr1[4]+afr1[0-3] | bar | lgkm0 | 16 MFMA | bar
//  (1,1): stage B_kc1(t+1) | ds afr1[4-7] | vmcnt(4)+bar | lgkm0 | 16 MFMA | bar
// vmcnt ledger (2 loads/phase/thread, R10-verified): entering (0,0)(t): outstanding
// = kc1(t)[4]; +2+2 => 8; gate vmcnt(4) retires kc1(t). +2+2 => 8 at (1,1); gate
// vmcnt(4) retires kc0(t+1). Tail: NT-1 stages nothing; (0,1) gate = vmcnt(0);
// (1,1) gate = plain. Prologue: 8 loads ledger-order; vmcnt(4) retires kc0(0).
// WAR/RAW per-region verified R10; extra barriers only strengthen.
// L2 supertiling (R6: FETCH 295->197MB): 4x4 tile supertiles per expert.
// MFMA swapped (Aop=weights bfr, Bop=tokens afr); C/D per R3 (verified):
//   acc[j][i] lane l reg r -> C[m0+wr*128+j*16+(l&15)][n0+wc*64+i*16+(l>>4)*4+r]
template <int K, int N, bool GELU_OUT>
__global__ __launch_bounds__(512, 2) void moe_gemm256_kernel(
    const u16* __restrict__ A, const u16* __restrict__ Bt,
    const float* __restrict__ bias, void* __restrict__ Out) {
  extern __shared__ __align__(16) char smem_raw[];
  constexpr int TX = N / 256;
  constexpr int NT = K / 64;
  static_assert(NT % 2 == 0 && NT >= 4, "K-tile count");
  static_assert(TX == 4 || TX == 16, "supertile map assumes TX in {4,16}");

  const int bid = blockIdx.x;
  const int e = bid & 7;          // XCD swizzle: nwg%8==0, one expert per XCD
  const int idx = bid >> 3;
  constexpr int STC = TX / 4;     // supertile cols
  const int st = idx >> 4;
  const int win = idx & 15;
  const int m0 = ((st / STC) * 4 + (win >> 2)) * 256;
  const int n0 = ((st % STC) * 4 + (win & 3)) * 256;

  const u16* Ae = A + (size_t)e * CAP * K;
  const u16* Be = Bt + (size_t)e * N * K;

  const int tid = threadIdx.x;
  const int l = tid & 63;
  const int w = tid >> 6;
  const int wr = w >> 2;          // 0..1 (M)
  const int wc = w & 3;           // 0..3 (N)
  const int g = l >> 4;           // 0..3 (k-unit within 32-chunk)
  const int rl = l & 15;

  // ---- ds_read byte offsets, REGION-LOCAL (swizzled, loop-invariant) ----
  int aoff[8], boff[4];
#pragma unroll
  for (int j = 0; j < 8; ++j) {
    int r = wr * 128 + j * 16 + rl;          // 0..255
    int r7 = r & 127;
    int lu = (r >> 7) * 4 + g;
    aoff[j] = r7 * 128 + ((lu ^ (r7 & 7)) << 4);
  }
#pragma unroll
  for (int i = 0; i < 4; ++i) {
    int r = wc * 64 + i * 16 + rl;           // 0..255
    int r7 = r & 127;
    int lu = (r >> 7) * 4 + g;
    boff[i] = r7 * 128 + ((lu ^ (r7 & 7)) << 4);
  }

  // ---- staging: linear LDS dest + inverse-swizzled global source (rule #21) ----
  auto mkoff = [&](int sidx, int base0) -> size_t {
    int lrow = sidx >> 3, pu = sidx & 7;
    int lu = pu ^ (lrow & 7);
    int r = lrow + ((lu & 4) << 5);
    return (size_t)(base0 + r) * K + (lu & 3) * 8;
  };
  const u16* gA0 = Ae + mkoff(tid, m0);
  const u16* gA1 = Ae + mkoff(512 + tid, m0);
  const u16* gB0 = Be + mkoff(tid, n0);
  const u16* gB1 = Be + mkoff(512 + tid, n0);
  const int dL0 = tid * 16;          // region-local dest slot (thread)
  const int dL1 = 8192 + tid * 16;   // region-local dest slot (thread+512)

  f32x4 acc[8][4] = {};
  bf16x8 bfr[4];   // persists across the (kc,0)->(kc,1) phase pair

  // ---- one phase: {stage | ds | [vmcnt]+bar | lgkm0 | 16 MFMA | bar} ----
  auto phase = [&](auto KCc, auto MHc, auto SWc, auto GNc, auto CLOSEc,
                   const char* bufr, char* bufs, const int stE) {
    constexpr int KC = decltype(KCc)::value;
    constexpr int MH = decltype(MHc)::value;
    constexpr int SW = decltype(SWc)::value;     // 0=stage A, 1=stage B, 2=none
    constexpr int GN = decltype(GNc)::value;     // >=0: vmcnt(GN)+barrier; -1: plain
    constexpr bool CLOSE = decltype(CLOSEc)::value;
    if constexpr (SW == 0) {
      async_ld16(gA0 + stE + KC * 32, bufs + KC * 16384 + dL0);
      async_ld16(gA1 + stE + KC * 32, bufs + KC * 16384 + dL1);
    } else if constexpr (SW == 1) {
      async_ld16(gB0 + stE + KC * 32, bufs + 32768 + KC * 16384 + dL0);
      async_ld16(gB1 + stE + KC * 32, bufs + 32768 + KC * 16384 + dL1);
    }
    const char* ra = bufr + KC * 16384;
    const char* rb = bufr + 32768 + KC * 16384;
    bf16x8 afr[4];
    if constexpr (MH == 0) {
#pragma unroll
      for (int i = 0; i < 4; ++i) bfr[i] = *(const bf16x8*)(rb + boff[i]);
    }
#pragma unroll
    for (int j = 0; j < 4; ++j) afr[j] = *(const bf16x8*)(ra + aoff[MH * 4 + j]);
    if constexpr (GN >= 0) {
      asm volatile("s_waitcnt vmcnt(%0)\n\ts_barrier" :: "n"(GN) : "memory");
    } else {
      __builtin_amdgcn_s_barrier();
    }
    asm volatile("s_waitcnt lgkmcnt(0)" ::: "memory");
    __builtin_amdgcn_sched_barrier(0);   // rule #18
    __builtin_amdgcn_s_setprio(1);
#pragma unroll
    for (int j = 0; j < 4; ++j)
#pragma unroll
      for (int i = 0; i < 4; ++i)
        acc[MH * 4 + j][i] = __builtin_amdgcn_mfma_f32_16x16x32_bf16(
            bfr[i], afr[j], acc[MH * 4 + j][i], 0, 0, 0);
    __builtin_amdgcn_s_setprio(0);
    if constexpr (CLOSE) __builtin_amdgcn_s_barrier();   // m201 closing bracket
  };

  // ---- one K-tile (J = t&1; ST: stage tile t+1; LAST: tail gates) ----
  auto tile = [&](auto Jc, auto STc, auto LASTc) {
    constexpr int J = decltype(Jc)::value;
    constexpr bool STg = decltype(STc)::value;
    constexpr bool LAST = decltype(LASTc)::value;
    const char* bufr = smem_raw + J * 65536;
    char* bufs = (char*)smem_raw + (J ^ 1) * 65536;
    constexpr int SA = STg ? 0 : 2;
    constexpr int SB = STg ? 1 : 2;
    const int stE = (J + 1) * 64;   // elems from current pair base
    phase(ic<0>{}, ic<0>{}, ic<SA>{}, ic<-1>{}, std::true_type{}, bufr, bufs, stE);
    phase(ic<0>{}, ic<1>{}, ic<SB>{}, ic<(LAST ? 0 : 4)>{}, std::true_type{}, bufr, bufs, stE);
    phase(ic<1>{}, ic<0>{}, ic<SA>{}, ic<-1>{}, std::true_type{}, bufr, bufs, stE);
    phase(ic<1>{}, ic<1>{}, ic<SB>{}, ic<(LAST ? -1 : 4)>{},
          std::integral_constant<bool, !LAST>{}, bufr, bufs, stE);
  };

  // ---- prologue: stage tile 0 in ledger order; retire kc0(0) ----
  async_ld16(gA0, smem_raw + dL0);
  async_ld16(gA1, smem_raw + dL1);
  async_ld16(gB0, smem_raw + 32768 + dL0);
  async_ld16(gB1, smem_raw + 32768 + dL1);
  async_ld16(gA0 + 32, smem_raw + 16384 + dL0);
  async_ld16(gA1 + 32, smem_raw + 16384 + dL1);
  async_ld16(gB0 + 32, smem_raw + 49152 + dL0);
  async_ld16(gB1 + 32, smem_raw + 49152 + dL1);
  asm volatile("s_waitcnt vmcnt(4)\n\ts_barrier" ::: "memory");
  __builtin_amdgcn_sched_barrier(0);

  // ---- main: pairs of tiles ----
#pragma unroll 1
  for (int pr = 0; pr < NT / 2 - 1; ++pr) {
    tile(ic<0>{}, std::true_type{}, std::false_type{});
    tile(ic<1>{}, std::true_type{}, std::false_type{});
    gA0 += 128; gA1 += 128; gB0 += 128; gB1 += 128;   // 2 tiles * 64 elems
  }
  tile(ic<0>{}, std::true_type{}, std::false_type{});   // NT-2: stages NT-1
  tile(ic<1>{}, std::false_type{}, std::true_type{});   // NT-1: tail

  // ---- epilogue (R3-verified mapping) ----
  const float* be = bias + (size_t)e * N;
  const int mb = m0 + wr * 128 + rl;
  const int nb = n0 + wc * 64 + g * 4;
  if constexpr (GELU_OUT) {
    u16* Oe = (u16*)Out + (size_t)e * (size_t)CAP * N;
#pragma unroll
    for (int j = 0; j < 8; ++j) {
      int m = mb + j * 16;
#pragma unroll
      for (int i = 0; i < 4; ++i) {
        int n = nb + i * 16;
        float4 bv = *(const float4*)(be + n);
        ushort4 o;
        o.x = f2bf(gelu_f(acc[j][i][0] + bv.x));
        o.y = f2bf(gelu_f(acc[j][i][1] + bv.y));
        o.z = f2bf(gelu_f(acc[j][i][2] + bv.z));
        o.w = f2bf(gelu_f(acc[j][i][3] + bv.w));
        *(ushort4*)(Oe + (size_t)m * N + n) = o;
      }
    }
  } else {
    float* Oe = (float*)Out + (size_t)e * (size_t)CAP * N;
#pragma unroll
    for (int j = 0; j < 8; ++j) {
      int m = mb + j * 16;
#pragma unroll
      for (int i = 0; i < 4; ++i) {
        int n = nb + i * 16;
        float4 bv = *(const float4*)(be + n);
        float4 o;
        o.x = acc[j][i][0] + bv.x;
        o.y = acc[j][i][1] + bv.y;
        o.z = acc[j][i][2] + bv.z;
        o.w = acc[j][i][3] + bv.w;
        *(float4*)(Oe + (size_t)m * N + n) = o;
      }
    }
  }
}

extern "C" void kernel_launch(void* const* d_in, const int* in_sizes, int n_in,
                              void* d_out, int out_size, void* d_ws, size_t ws_size,
                              hipStream_t stream) {
  const float* x  = (const float*)d_in[0];
  // d_in[1] = expert_size (equal splits by construction; unused)
  const float* w1 = (const float*)d_in[2];
  const float* b1 = (const float*)d_in[3];
  const float* w2 = (const float*)d_in[4];
  const float* b2 = (const float*)d_in[5];
  float* out = (float*)d_out;

  char* wsp = (char*)d_ws;
  u16* x_bf = (u16*)(wsp);                             // 64 MiB
  u16* w1t  = (u16*)(wsp + (size_t)67108864);          // 64 MiB  [E][DHID][DIN]
  u16* w2t  = (u16*)(wsp + (size_t)134217728);         // 64 MiB  [E][DOUT][DHID]
  u16* h    = (u16*)(wsp + (size_t)201326592);         // 256 MiB [NTOK][DHID]

  hipFuncSetAttribute(reinterpret_cast<const void*>(moe_gemm256_kernel<DIN, DHID, true>),
                      hipFuncAttributeMaxDynamicSharedMemorySize, 131072);
  hipFuncSetAttribute(reinterpret_cast<const void*>(moe_gemm256_kernel<DHID, DOUTD, false>),
                      hipFuncAttributeMaxDynamicSharedMemorySize, 131072);

  convert_bf16_kernel<<<(NTOK * DIN) / (256 * 8), 256, 0, stream>>>(x, x_bf);
  transpose_bf16_kernel<<<dim3(DHID / 64, DIN / 64, NE), 256, 0, stream>>>(w1, w1t, DIN, DHID);
  transpose_bf16_kernel<<<dim3(DOUTD / 64, DHID / 64, NE), 256, 0, stream>>>(w2, w2t, DHID, DOUTD);

  moe_gemm256_kernel<DIN, DHID, true>
      <<<dim3(NE * (CAP / 256) * (DHID / 256)), 512, 131072, stream>>>(x_bf, w1t, b1, h);
  moe_gemm256_kernel<DHID, DOUTD, false>
      <<<dim3(NE * (CAP / 256) * (DOUTD / 256)), 512, 131072, stream>>>(h, w2t, b2, out);
}

// Round 12
// 718.061 us; speedup vs baseline: 1.0091x; 1.0091x over previous
//
#include <hip/hip_runtime.h>
#include <hip/hip_bf16.h>
#include <type_traits>

#define NE 8
#define DIN 1024
#define DHID 4096
#define DOUTD 1024
#define NTOK 32768
#define CAP (NTOK / NE)  // 4096 tokens per expert

typedef unsigned short u16;
typedef __attribute__((ext_vector_type(8))) short bf16x8;   // 8 bf16 = 4 VGPR
typedef __attribute__((ext_vector_type(4))) float f32x4;

template <int I> using ic = std::integral_constant<int, I>;

__device__ __forceinline__ u16 f2bf(float x) {
  unsigned u = __builtin_bit_cast(unsigned, x);
  u += 0x7fffu + ((u >> 16) & 1u);   // RNE; finite normals
  return (u16)(u >> 16);
}

// tanh-form GELU (max dev from erf-form ~3e-4; threshold headroom ~4.6x; R4-R11-verified)
__device__ __forceinline__ float gelu_f(float x) {
  float u = 0.7978845608028654f * x * (1.0f + 0.044715f * x * x);
  float t = __expf(-2.0f * fabsf(u));
  float r = __fdividef(2.0f * t, 1.0f + t);   // 1 - tanh|u|
  float th = copysignf(1.0f - r, u);
  return 0.5f * x * (1.0f + th);
}

__device__ __forceinline__ void async_ld16(const void* g, void* l) {
  __builtin_amdgcn_global_load_lds(
      (const __attribute__((address_space(1))) unsigned int*)g,
      (__attribute__((address_space(3))) unsigned int*)l, 16, 0, 0);
}

// ---------------- fp32 -> bf16, 8 elems/thread ----------------
__global__ __launch_bounds__(256) void convert_bf16_kernel(const float* __restrict__ in,
                                                           u16* __restrict__ out) {
  size_t i = ((size_t)blockIdx.x * 256 + threadIdx.x) * 8;
  float4 a = *(const float4*)(in + i);
  float4 b = *(const float4*)(in + i + 4);
  uint4 o;
  o.x = (unsigned)f2bf(a.x) | ((unsigned)f2bf(a.y) << 16);
  o.y = (unsigned)f2bf(a.z) | ((unsigned)f2bf(a.w) << 16);
  o.z = (unsigned)f2bf(b.x) | ((unsigned)f2bf(b.y) << 16);
  o.w = (unsigned)f2bf(b.z) | ((unsigned)f2bf(b.w) << 16);
  *(uint4*)(out + i) = o;
}

// ------------- [E][K][N] fp32 -> [E][N][K] bf16 (64x64 LDS-tiled) -------------
__global__ __launch_bounds__(256) void transpose_bf16_kernel(const float* __restrict__ in,
                                                             u16* __restrict__ out,
                                                             int K, int N) {
  __shared__ __align__(16) u16 tile[64 * 72];
  const int e = blockIdx.z;
  const int n0 = blockIdx.x * 64;
  const int k0 = blockIdx.y * 64;
  const float* inp = in + (size_t)e * K * N;
  u16* outp = out + (size_t)e * N * K;
  const int t = threadIdx.x;
  const int kr = t >> 4;
  const int nc = (t & 15) * 4;
#pragma unroll
  for (int rr = 0; rr < 4; ++rr) {
    int kl = rr * 16 + kr;
    float4 v = *(const float4*)(inp + (size_t)(k0 + kl) * N + n0 + nc);
    tile[(nc + 0) * 72 + kl] = f2bf(v.x);
    tile[(nc + 1) * 72 + kl] = f2bf(v.y);
    tile[(nc + 2) * 72 + kl] = f2bf(v.z);
    tile[(nc + 3) * 72 + kl] = f2bf(v.w);
  }
  __syncthreads();
  const int nr = t >> 3;
  const int kc = (t & 7) * 8;
#pragma unroll
  for (int it = 0; it < 2; ++it) {
    int nl = it * 32 + nr;
    bf16x8 w = *(const bf16x8*)(tile + nl * 72 + kc);
    *(bf16x8*)(outp + (size_t)(n0 + nl) * K + k0 + kc) = w;
  }
}

// -------- grouped GEMM, 256x256, BK=64, dbuf-2, FINE 4-PHASE interleave (T3+T4) --------
// == R10 EXACT (best measured: 715 us total, 817 TF/GEMM). R11's closing-barrier
// variant regressed (-4.5%) and is reverted: K-chunk-partitioned phases already
// have a gate per phase pair; the extra bracket only added sync latency.
// C[e] = A[e] (CAP x K bf16 row-major) @ Bt[e]^T (Bt: N x K bf16 row-major).
// 8 waves (2M x 4N), per-wave 128x64, MFMA 16x16x32, acc f32x4[8][4] (128 AGPR).
// R9 lesson: unified regs (~104 VGPR + 128 AGPR) => 2 waves/SIMD, 1 block/CU
// regardless of LDS; <=128 total spills catastrophically (R8). Intra-block
// schedule is the only lever; R5-R11 bracketed it: 755/779/817/779 -> R10 wins.
// LDS: 2 buffers x 64KB; buffer = 4 regions of 16KB: {A_kc0@0, A_kc1@16K,
// B_kc0@32K, B_kc1@48K}. Region layout (R1-R10, 0 conflicts): [128 lds-rows]
// [8 x 16B units]; global (r,k in 32-chunk): lds_row=r&127, lu=(r>>7)*4+(k>>3),
// phys unit=lu^(lds_row&7) (T2); staged linear-dest + inverse-swizzled global
// source (rule #21). Phase (kc,*) reads ONLY region kc => staging order
// A_kc0,B_kc0,A_kc1,B_kc1 gives counted gates (never drain, T4) with 2-3 phase cover.
// Per K-tile t (read buf P=t&1, stage t+1 into Q=P^1), 4 phases (kc,mh):
//  (0,0): stage A_kc0(t+1) | ds bfr0[4]+afr0[0-3] | bar | lgkm0 | 16 MFMA
//  (0,1): stage B_kc0(t+1) | ds afr0[4-7] | vmcnt(4)+bar | lgkm0 | 16 MFMA
//  (1,0): stage A_kc1(t+1) | ds bfr1[4]+afr1[0-3] | bar | lgkm0 | 16 MFMA
//  (1,1): stage B_kc1(t+1) | ds afr1[4-7] | vmcnt(4)+bar | lgkm0 | 16 MFMA
// vmcnt ledger (2 loads/phase/thread, induction verified): entering (0,0)(t):
// outstanding = kc1(t) [4]. +2 at (0,0), +2 at (0,1) => 8; GATE vmcnt(4) retires
// kc1(t) (read NEXT phase, staged 2-3 phases ago). +2+2 => 8 at (1,1); GATE
// vmcnt(4) retires kc0(t+1). Steady state never drains (T4). Tail: tile NT-1
// stages nothing; its (0,1) gate = vmcnt(0); (1,1) gate = plain barrier.
// Prologue: 8 loads of tile 0 in ledger order; vmcnt(4) retires kc0(0).
// WAR: each region's stage is >=2 barriers after that region's last reader's
// lgkm0. RAW: each region's first read is after the gate retiring its stage.
// L2 supertiling (R6: FETCH 295->197MB): 4x4 tile supertiles per expert.
// MFMA swapped (Aop=weights bfr, Bop=tokens afr); C/D per R3 (verified):
//   acc[j][i] lane l reg r -> C[m0+wr*128+j*16+(l&15)][n0+wc*64+i*16+(l>>4)*4+r]
template <int K, int N, bool GELU_OUT>
__global__ __launch_bounds__(512, 2) void moe_gemm256_kernel(
    const u16* __restrict__ A, const u16* __restrict__ Bt,
    const float* __restrict__ bias, void* __restrict__ Out) {
  extern __shared__ __align__(16) char smem_raw[];
  constexpr int TX = N / 256;
  constexpr int NT = K / 64;
  static_assert(NT % 2 == 0 && NT >= 4, "K-tile count");
  static_assert(TX == 4 || TX == 16, "supertile map assumes TX in {4,16}");

  const int bid = blockIdx.x;
  const int e = bid & 7;          // XCD swizzle: nwg%8==0, one expert per XCD
  const int idx = bid >> 3;
  constexpr int STC = TX / 4;     // supertile cols
  const int st = idx >> 4;
  const int win = idx & 15;
  const int m0 = ((st / STC) * 4 + (win >> 2)) * 256;
  const int n0 = ((st % STC) * 4 + (win & 3)) * 256;

  const u16* Ae = A + (size_t)e * CAP * K;
  const u16* Be = Bt + (size_t)e * N * K;

  const int tid = threadIdx.x;
  const int l = tid & 63;
  const int w = tid >> 6;
  const int wr = w >> 2;          // 0..1 (M)
  const int wc = w & 3;           // 0..3 (N)
  const int g = l >> 4;           // 0..3 (k-unit within 32-chunk)
  const int rl = l & 15;

  // ---- ds_read byte offsets, REGION-LOCAL (swizzled, loop-invariant) ----
  int aoff[8], boff[4];
#pragma unroll
  for (int j = 0; j < 8; ++j) {
    int r = wr * 128 + j * 16 + rl;          // 0..255
    int r7 = r & 127;
    int lu = (r >> 7) * 4 + g;
    aoff[j] = r7 * 128 + ((lu ^ (r7 & 7)) << 4);
  }
#pragma unroll
  for (int i = 0; i < 4; ++i) {
    int r = wc * 64 + i * 16 + rl;           // 0..255
    int r7 = r & 127;
    int lu = (r >> 7) * 4 + g;
    boff[i] = r7 * 128 + ((lu ^ (r7 & 7)) << 4);
  }

  // ---- staging: linear LDS dest + inverse-swizzled global source (rule #21) ----
  auto mkoff = [&](int sidx, int base0) -> size_t {
    int lrow = sidx >> 3, pu = sidx & 7;
    int lu = pu ^ (lrow & 7);
    int r = lrow + ((lu & 4) << 5);
    return (size_t)(base0 + r) * K + (lu & 3) * 8;
  };
  const u16* gA0 = Ae + mkoff(tid, m0);
  const u16* gA1 = Ae + mkoff(512 + tid, m0);
  const u16* gB0 = Be + mkoff(tid, n0);
  const u16* gB1 = Be + mkoff(512 + tid, n0);
  const int dL0 = tid * 16;          // region-local dest slot (thread)
  const int dL1 = 8192 + tid * 16;   // region-local dest slot (thread+512)

  f32x4 acc[8][4] = {};
  bf16x8 bfr[4];   // persists across the (kc,0)->(kc,1) phase pair

  // ---- one phase ----
  auto phase = [&](auto KCc, auto MHc, auto SWc, auto GNc,
                   const char* bufr, char* bufs, const int stE) {
    constexpr int KC = decltype(KCc)::value;
    constexpr int MH = decltype(MHc)::value;
    constexpr int SW = decltype(SWc)::value;     // 0=stage A, 1=stage B, 2=none
    constexpr int GN = decltype(GNc)::value;     // >=0: vmcnt(GN)+barrier; -1: plain
    if constexpr (SW == 0) {
      async_ld16(gA0 + stE + KC * 32, bufs + KC * 16384 + dL0);
      async_ld16(gA1 + stE + KC * 32, bufs + KC * 16384 + dL1);
    } else if constexpr (SW == 1) {
      async_ld16(gB0 + stE + KC * 32, bufs + 32768 + KC * 16384 + dL0);
      async_ld16(gB1 + stE + KC * 32, bufs + 32768 + KC * 16384 + dL1);
    }
    const char* ra = bufr + KC * 16384;
    const char* rb = bufr + 32768 + KC * 16384;
    bf16x8 afr[4];
    if constexpr (MH == 0) {
#pragma unroll
      for (int i = 0; i < 4; ++i) bfr[i] = *(const bf16x8*)(rb + boff[i]);
    }
#pragma unroll
    for (int j = 0; j < 4; ++j) afr[j] = *(const bf16x8*)(ra + aoff[MH * 4 + j]);
    if constexpr (GN >= 0) {
      asm volatile("s_waitcnt vmcnt(%0)\n\ts_barrier" :: "n"(GN) : "memory");
    } else {
      __builtin_amdgcn_s_barrier();
    }
    asm volatile("s_waitcnt lgkmcnt(0)" ::: "memory");
    __builtin_amdgcn_sched_barrier(0);   // rule #18
    __builtin_amdgcn_s_setprio(1);
#pragma unroll
    for (int j = 0; j < 4; ++j)
#pragma unroll
      for (int i = 0; i < 4; ++i)
        acc[MH * 4 + j][i] = __builtin_amdgcn_mfma_f32_16x16x32_bf16(
            bfr[i], afr[j], acc[MH * 4 + j][i], 0, 0, 0);
    __builtin_amdgcn_s_setprio(0);
  };

  // ---- one K-tile (J = t&1; ST: stage tile t+1; LAST: tail gates) ----
  auto tile = [&](auto Jc, auto STc, auto LASTc) {
    constexpr int J = decltype(Jc)::value;
    constexpr bool STg = decltype(STc)::value;
    constexpr bool LAST = decltype(LASTc)::value;
    const char* bufr = smem_raw + J * 65536;
    char* bufs = (char*)smem_raw + (J ^ 1) * 65536;
    constexpr int SA = STg ? 0 : 2;
    constexpr int SB = STg ? 1 : 2;
    const int stE = (J + 1) * 64;   // elems from current pair base
    phase(ic<0>{}, ic<0>{}, ic<SA>{}, ic<-1>{}, bufr, bufs, stE);
    phase(ic<0>{}, ic<1>{}, ic<SB>{}, ic<(LAST ? 0 : 4)>{}, bufr, bufs, stE);
    phase(ic<1>{}, ic<0>{}, ic<SA>{}, ic<-1>{}, bufr, bufs, stE);
    phase(ic<1>{}, ic<1>{}, ic<SB>{}, ic<(LAST ? -1 : 4)>{}, bufr, bufs, stE);
  };

  // ---- prologue: stage tile 0 in ledger order; retire kc0(0) ----
  async_ld16(gA0, smem_raw + dL0);
  async_ld16(gA1, smem_raw + dL1);
  async_ld16(gB0, smem_raw + 32768 + dL0);
  async_ld16(gB1, smem_raw + 32768 + dL1);
  async_ld16(gA0 + 32, smem_raw + 16384 + dL0);
  async_ld16(gA1 + 32, smem_raw + 16384 + dL1);
  async_ld16(gB0 + 32, smem_raw + 49152 + dL0);
  async_ld16(gB1 + 32, smem_raw + 49152 + dL1);
  asm volatile("s_waitcnt vmcnt(4)\n\ts_barrier" ::: "memory");
  __builtin_amdgcn_sched_barrier(0);

  // ---- main: pairs of tiles ----
#pragma unroll 1
  for (int pr = 0; pr < NT / 2 - 1; ++pr) {
    tile(ic<0>{}, std::true_type{}, std::false_type{});
    tile(ic<1>{}, std::true_type{}, std::false_type{});
    gA0 += 128; gA1 += 128; gB0 += 128; gB1 += 128;   // 2 tiles * 64 elems
  }
  tile(ic<0>{}, std::true_type{}, std::false_type{});   // NT-2: stages NT-1
  tile(ic<1>{}, std::false_type{}, std::true_type{});   // NT-1: tail

  // ---- epilogue (R3-verified mapping) ----
  const float* be = bias + (size_t)e * N;
  const int mb = m0 + wr * 128 + rl;
  const int nb = n0 + wc * 64 + g * 4;
  if constexpr (GELU_OUT) {
    u16* Oe = (u16*)Out + (size_t)e * (size_t)CAP * N;
#pragma unroll
    for (int j = 0; j < 8; ++j) {
      int m = mb + j * 16;
#pragma unroll
      for (int i = 0; i < 4; ++i) {
        int n = nb + i * 16;
        float4 bv = *(const float4*)(be + n);
        ushort4 o;
        o.x = f2bf(gelu_f(acc[j][i][0] + bv.x));
        o.y = f2bf(gelu_f(acc[j][i][1] + bv.y));
        o.z = f2bf(gelu_f(acc[j][i][2] + bv.z));
        o.w = f2bf(gelu_f(acc[j][i][3] + bv.w));
        *(ushort4*)(Oe + (size_t)m * N + n) = o;
      }
    }
  } else {
    float* Oe = (float*)Out + (size_t)e * (size_t)CAP * N;
#pragma unroll
    for (int j = 0; j < 8; ++j) {
      int m = mb + j * 16;
#pragma unroll
      for (int i = 0; i < 4; ++i) {
        int n = nb + i * 16;
        float4 bv = *(const float4*)(be + n);
        float4 o;
        o.x = acc[j][i][0] + bv.x;
        o.y = acc[j][i][1] + bv.y;
        o.z = acc[j][i][2] + bv.z;
        o.w = acc[j][i][3] + bv.w;
        *(float4*)(Oe + (size_t)m * N + n) = o;
      }
    }
  }
}

extern "C" void kernel_launch(void* const* d_in, const int* in_sizes, int n_in,
                              void* d_out, int out_size, void* d_ws, size_t ws_size,
                              hipStream_t stream) {
  const float* x  = (const float*)d_in[0];
  // d_in[1] = expert_size (equal splits by construction; unused)
  const float* w1 = (const float*)d_in[2];
  const float* b1 = (const float*)d_in[3];
  const float* w2 = (const float*)d_in[4];
  const float* b2 = (const float*)d_in[5];
  float* out = (float*)d_out;

  char* wsp = (char*)d_ws;
  u16* x_bf = (u16*)(wsp);                             // 64 MiB
  u16* w1t  = (u16*)(wsp + (size_t)67108864);          // 64 MiB  [E][DHID][DIN]
  u16* w2t  = (u16*)(wsp + (size_t)134217728);         // 64 MiB  [E][DOUT][DHID]
  u16* h    = (u16*)(wsp + (size_t)201326592);         // 256 MiB [NTOK][DHID]

  hipFuncSetAttribute(reinterpret_cast<const void*>(moe_gemm256_kernel<DIN, DHID, true>),
                      hipFuncAttributeMaxDynamicSharedMemorySize, 131072);
  hipFuncSetAttribute(reinterpret_cast<const void*>(moe_gemm256_kernel<DHID, DOUTD, false>),
                      hipFuncAttributeMaxDynamicSharedMemorySize, 131072);

  convert_bf16_kernel<<<(NTOK * DIN) / (256 * 8), 256, 0, stream>>>(x, x_bf);
  transpose_bf16_kernel<<<dim3(DHID / 64, DIN / 64, NE), 256, 0, stream>>>(w1, w1t, DIN, DHID);
  transpose_bf16_kernel<<<dim3(DOUTD / 64, DHID / 64, NE), 256, 0, stream>>>(w2, w2t, DHID, DOUTD);

  moe_gemm256_kernel<DIN, DHID, true>
      <<<dim3(NE * (CAP / 256) * (DHID / 256)), 512, 131072, stream>>>(x_bf, w1t, b1, h);
  moe_gemm256_kernel<DHID, DOUTD, false>
      <<<dim3(NE * (CAP / 256) * (DOUTD / 256)), 512, 131072, stream>>>(h, w2t, b2, out);
}